// Round 1
// 335.067 us; speedup vs baseline: 1.0117x; 1.0117x over previous
//
#include <hip/hip_runtime.h>
#include <math.h>

// Problem constants (fixed by setup_inputs)
#define Bq   8
#define Cc   3
#define Hh   128     // h = H/8
#define Ww   256     // w = W/8
#define Mm   32
#define HW   (Hh*Ww) // 32768
#define HIMG 1024
#define WIMG 2048

// ---------------------------------------------------------------------------
// Kernel 1: depth + channel-major normals from disp. Tiny (~2-3 us): reads
// disp (1 MB), writes depth+normal (4.2 MB, stays L3-hot for k_pool_planes).
// Hoisted out of the pool kernel so the planes reduction can overlap the
// 201 MB img stream instead of serializing after it.
// ---------------------------------------------------------------------------
__global__ void k_dn(const float* __restrict__ disp,
                     const float* __restrict__ intrs,
                     const float* __restrict__ baseline,
                     float* __restrict__ depth,
                     float* __restrict__ normal) {
    int idx = blockIdx.x * 256 + threadIdx.x;   // B*HW threads
    int b = idx >> 15;
    int p = idx & (HW - 1);
    int y = p >> 8;
    int x = p & (Ww - 1);
    float focal = 0.5f * (intrs[b * 9 + 0] + intrs[b * 9 + 4]);
    float k = baseline[b] * focal * (1.0f / 2048.0f);
    const float* db = disp + (size_t)b * HW;
    float Dc  = k / db[p];
    float Dxm = (x > 0)      ? k / db[p - 1]  : 0.0f;
    float Dxp = (x < Ww - 1) ? k / db[p + 1]  : 0.0f;
    float Dym = (y > 0)      ? k / db[p - Ww] : 0.0f;
    float Dyp = (y < Hh - 1) ? k / db[p + Ww] : 0.0f;
    float gx = 0.5f * (Dxp - Dxm);
    float gy = 0.5f * (Dyp - Dym);
    float invn = 1.0f / sqrtf(gx * gx + gy * gy + 1.0f);
    depth[idx] = Dc;
    // channel-major (3,h,w) per b — k_planes' torch-view channel-mixing
    // quirk depends on this exact flatten.
    float* nb = normal + (size_t)b * 3 * HW;
    nb[p]          = -gx * invn;
    nb[HW + p]     = -gy * invn;
    nb[2 * HW + p] =  invn;
}

// ---------------------------------------------------------------------------
// Kernel 2 (merged): blocks [0, Bq*Mm) do the per-(b,m) softmax-weighted
// depth/normal sums + homography (masks stream overlaps the img stream);
// blocks [Bq*Mm, Bq*Mm + Bq*Hh/2) do the 8x8 average pool (dominant 201 MB
// HBM stream, packed float4 output for k_blend's gathers). 512-thread
// blocks (8 waves) so multiple blocks of mixed roles co-reside per CU.
// Block-level role split = no wave divergence.
// ---------------------------------------------------------------------------
__global__ __launch_bounds__(512) void k_pool_planes(
        const float* __restrict__ img, float4* __restrict__ img_p,
        const float* __restrict__ masks,
        const float* __restrict__ depth, const float* __restrict__ normal,
        const float* __restrict__ intrs, const float* __restrict__ baseline,
        float* __restrict__ hm) {
    int blk = blockIdx.x;
    int tid = threadIdx.x;
    __shared__ float lds[5][8];
    if (blk < Bq * Mm) {
        // ---- planes role: one block per (b,m). Single pass (softmax
        // shift-invariance; masks~N(0,1), exp safe in fp32). Channel-mixed
        // normal reads n[3p..3p+2] for p=4i..4i+3 are exactly float4s
        // np[3i], np[3i+1], np[3i+2]. ----
        int bm = blk;
        int b = bm >> 5;
        const float4* mp = (const float4*)(masks + (size_t)bm * HW);
        const float4* dp = (const float4*)(depth + (size_t)b * HW);
        const float4* np = (const float4*)(normal + (size_t)b * 3 * HW);
        int lane = tid & 63, wid = tid >> 6;

        float se = 0.f, sd = 0.f, s0 = 0.f, s1 = 0.f, s2 = 0.f;
        #pragma unroll 4
        for (int kk = 0; kk < HW / 4 / 512; kk++) {   // exactly 16 iterations
            int i = tid + kk * 512;
            float4 mk  = mp[i];
            float4 d4  = dp[i];
            float4 n0v = np[3 * i], n1v = np[3 * i + 1], n2v = np[3 * i + 2];
            float e0 = __expf(mk.x), e1 = __expf(mk.y);
            float e2 = __expf(mk.z), e3 = __expf(mk.w);
            se += (e0 + e1) + (e2 + e3);
            sd = fmaf(e0, d4.x, fmaf(e1, d4.y, fmaf(e2, d4.z, fmaf(e3, d4.w, sd))));
            // p=4i+j reads normal linear idx 12i+3j .. 12i+3j+2:
            s0 = fmaf(e0, n0v.x, fmaf(e1, n0v.w, fmaf(e2, n1v.z, fmaf(e3, n2v.y, s0))));
            s1 = fmaf(e0, n0v.y, fmaf(e1, n1v.x, fmaf(e2, n1v.w, fmaf(e3, n2v.z, s1))));
            s2 = fmaf(e0, n0v.z, fmaf(e1, n1v.y, fmaf(e2, n2v.x, fmaf(e3, n2v.w, s2))));
        }
        float vals[5] = {se, sd, s0, s1, s2};
        #pragma unroll
        for (int j = 0; j < 5; j++) {
            float v = vals[j];
            #pragma unroll
            for (int off = 32; off; off >>= 1) v += __shfl_down(v, off, 64);
            if (lane == 0) lds[j][wid] = v;
        }
        __syncthreads();

        if (tid == 0) {
            float t[5];
            #pragma unroll
            for (int j = 0; j < 5; j++) {
                float r = 0.f;
                #pragma unroll
                for (int i = 0; i < 8; i++) r += lds[j][i];
                t[j] = r;
            }
            float inv_se = 1.0f / t[0];
            float pd = t[1] * inv_se;
            float n0 = t[2] * inv_se, n1 = t[3] * inv_se, n2 = t[4] * inv_se;
            const float* Km = intrs + b * 9;
            float a = Km[0], bb = Km[1], c = Km[2];
            float d = Km[3], e  = Km[4], f = Km[5];
            float g = Km[6], h2 = Km[7], i = Km[8];
            float det = a * (e * i - f * h2) - bb * (d * i - f * g) + c * (d * h2 - e * g);
            float invd = 1.0f / det;
            float ki[9] = {(e * i - f * h2) * invd, (c * h2 - bb * i) * invd, (bb * f - c * e) * invd,
                           (f * g - d * i) * invd, (a * i - c * g) * invd,  (c * d - a * f) * invd,
                           (d * h2 - e * g) * invd, (bb * g - a * h2) * invd, (a * e - bb * d) * invd};
            float s = baseline[b] / pd;
            // H_cal = I + s*e2*n^T (rows 0,1 identity; row 2 = (s n0, s n1, 1+s n2))
            float A[9] = {1.f, 0.f, 0.f, 0.f, 1.f, 0.f, s * n0, s * n1, 1.0f + s * n2};
            float T[9];
            #pragma unroll
            for (int r = 0; r < 3; r++)
                #pragma unroll
                for (int cc = 0; cc < 3; cc++)
                    T[r * 3 + cc] = Km[r * 3 + 0] * A[cc] + Km[r * 3 + 1] * A[3 + cc] + Km[r * 3 + 2] * A[6 + cc];
            #pragma unroll
            for (int r = 0; r < 2; r++)
                #pragma unroll
                for (int cc = 0; cc < 3; cc++)
                    hm[bm * 6 + r * 3 + cc] = T[r * 3 + 0] * ki[cc] + T[r * 3 + 1] * ki[3 + cc] + T[r * 3 + 2] * ki[6 + cc];
        }
    } else {
        // ---- pool role: one block per (b, 2-row group); thread = (row, x) ----
        int pb = blk - Bq * Mm;        // 0..511
        int b = pb >> 6;
        int y = ((pb & 63) << 1) | (tid >> 8);
        int x = tid & 255;
        float s[3];
        #pragma unroll
        for (int c = 0; c < 3; c++) {
            const float* base = img + ((size_t)(b * 3 + c) * HIMG + (size_t)y * 8) * WIMG + x * 8;
            float acc = 0.f;
            #pragma unroll
            for (int r = 0; r < 8; r++) {
                float4 u = *(const float4*)(base + (size_t)r * WIMG);
                float4 v = *(const float4*)(base + (size_t)r * WIMG + 4);
                acc += u.x + u.y + u.z + u.w + v.x + v.y + v.z + v.w;
            }
            s[c] = acc * (1.0f / 64.0f);
        }
        img_p[((size_t)(b * Hh + y)) * Ww + x] = make_float4(s[0], s[1], s[2], 0.f);
    }
}

// ---------------------------------------------------------------------------
// Kernel 3: per-pixel M-softmax blend with homography warp + bilinear sample
// (zeros padding, align_corners=True). 512-thread blocks: the 32-plane loop
// is split across two 256-thread halves (16 planes each, LDS combine) —
// halves the serial exp/gather chain per thread and doubles waves/CU for
// gather-latency hiding. All 16 mask loads issued up front; no max
// subtraction (shift-invariant, masks~N(0,1)). Validity folded into the
// bilinear weights (int clamps, one cmp+cndmask per edge).
// ---------------------------------------------------------------------------
__global__ __launch_bounds__(512) void k_blend(const float* __restrict__ masks,
                        const float* __restrict__ hm,
                        const float4* __restrict__ img_p,
                        float* __restrict__ out) {
    int bi = blockIdx.x;           // b*Hh + y
    int b = bi >> 7;
    int y = bi & (Hh - 1);
    int tid = threadIdx.x;
    int x = tid & (Ww - 1);
    int half = tid >> 8;           // 0: planes 0..15, 1: planes 16..31
    __shared__ float hs[Mm * 6];
    __shared__ float part[4][Ww];
    if (tid < Mm * 6) hs[tid] = hm[b * Mm * 6 + tid];
    __syncthreads();

    const float* mp = masks + (size_t)b * Mm * HW + (size_t)(half * 16) * HW
                    + (size_t)y * Ww + x;
    float mv[16];
    #pragma unroll
    for (int m = 0; m < 16; m++) mv[m] = mp[(size_t)m * HW];

    float xn = (2.0f * x - (float)(Ww - 1)) * (1.0f / (float)(Ww - 1));
    float yn = (2.0f * y - (float)(Hh - 1)) * (1.0f / (float)(Hh - 1));
    const float4* ip = img_p + (size_t)b * HW;
    const float* hb = hs + half * 16 * 6;

    float se = 0.f, a0 = 0.f, a1 = 0.f, a2 = 0.f;
    #pragma unroll 4
    for (int m = 0; m < 16; m++) {
        float e = __expf(mv[m]);
        se += e;
        float gx = fmaf(hb[m * 6 + 0], xn, fmaf(hb[m * 6 + 1], yn, hb[m * 6 + 2]));
        float gy = fmaf(hb[m * 6 + 3], xn, fmaf(hb[m * 6 + 4], yn, hb[m * 6 + 5]));
        float ix = (gx + 1.0f) * ((float)(Ww - 1) * 0.5f);
        float iy = (gy + 1.0f) * ((float)(Hh - 1) * 0.5f);
        float x0f = floorf(ix), y0f = floorf(iy);
        float wx1 = ix - x0f, wy1 = iy - y0f;
        float wx0 = 1.0f - wx1, wy0 = 1.0f - wy1;
        int x0i = (int)x0f, y0i = (int)y0f;
        // validity folded into weights: corner weight is zeroed when its
        // (pre-clamp) coordinate is outside [0, dim-1]. (unsigned) compare
        // handles both <0 and >dim-1 in one op.
        float vx0 = ((unsigned)x0i       < (unsigned)Ww) ? wx0 : 0.0f;
        float vx1 = ((unsigned)(x0i + 1) < (unsigned)Ww) ? wx1 : 0.0f;
        float vy0 = ((unsigned)y0i       < (unsigned)Hh) ? wy0 * e : 0.0f;
        float vy1 = ((unsigned)(y0i + 1) < (unsigned)Hh) ? wy1 * e : 0.0f;
        int xc0 = min(max(x0i, 0), Ww - 1);
        int xc1 = min(max(x0i + 1, 0), Ww - 1);
        int r0 = min(max(y0i, 0), Hh - 1) * Ww;
        int r1 = min(max(y0i + 1, 0), Hh - 1) * Ww;
        float4 t00 = ip[r0 + xc0];
        float4 t10 = ip[r0 + xc1];
        float4 t01 = ip[r1 + xc0];
        float4 t11 = ip[r1 + xc1];
        float w00 = vx0 * vy0, w10 = vx1 * vy0;
        float w01 = vx0 * vy1, w11 = vx1 * vy1;
        a0 = fmaf(w00, t00.x, fmaf(w10, t10.x, fmaf(w01, t01.x, fmaf(w11, t11.x, a0))));
        a1 = fmaf(w00, t00.y, fmaf(w10, t10.y, fmaf(w01, t01.y, fmaf(w11, t11.y, a1))));
        a2 = fmaf(w00, t00.z, fmaf(w10, t10.z, fmaf(w01, t01.z, fmaf(w11, t11.z, a2))));
    }
    if (half) {
        part[0][x] = se; part[1][x] = a0; part[2][x] = a1; part[3][x] = a2;
    }
    __syncthreads();
    if (!half) {
        se += part[0][x]; a0 += part[1][x]; a1 += part[2][x]; a2 += part[3][x];
        float inv = 1.0f / se;
        int o = y * Ww + x;
        float* ob = out + (size_t)b * 3 * HW;
        ob[o]          = a0 * inv;
        ob[HW + o]     = a1 * inv;
        ob[2 * HW + o] = a2 * inv;
    }
}

extern "C" void kernel_launch(void* const* d_in, const int* in_sizes, int n_in,
                              void* d_out, int out_size, void* d_ws, size_t ws_size,
                              hipStream_t stream) {
    const float* img      = (const float*)d_in[0];
    const float* masks    = (const float*)d_in[1];
    const float* disp     = (const float*)d_in[2];
    const float* intrs    = (const float*)d_in[3];
    const float* baseline = (const float*)d_in[4];
    float* out = (float*)d_out;

    // Workspace (floats): depth | normal | hm | img_p(float4) — offsets all
    // multiples of 4 floats so everything stays 16B-aligned. ~9.5 MB total.
    float* depth  = (float*)d_ws;                        // B*HW
    float* normal = depth + (size_t)Bq * HW;             // B*3*HW
    float* hm     = normal + (size_t)Bq * 3 * HW;        // B*M*6 = 1536
    float4* img_p = (float4*)(hm + (size_t)Bq * Mm * 6); // B*HW float4s

    // 3 dispatches: dn (tiny), then pool+planes merged (planes' mask stream
    // overlaps the 201 MB img stream; planes blocks dispatched first), then
    // blend (masks re-read is L3-resident).
    hipLaunchKernelGGL(k_dn, dim3(Bq * Hh), dim3(256), 0, stream,
                       disp, intrs, baseline, depth, normal);
    hipLaunchKernelGGL(k_pool_planes, dim3(Bq * Mm + Bq * Hh / 2), dim3(512), 0, stream,
                       img, img_p, masks, depth, normal, intrs, baseline, hm);
    hipLaunchKernelGGL(k_blend, dim3(Bq * Hh), dim3(512), 0, stream,
                       masks, hm, img_p, out);
}

// Round 2
// 330.840 us; speedup vs baseline: 1.0246x; 1.0128x over previous
//
#include <hip/hip_runtime.h>
#include <math.h>

// Problem constants (fixed by setup_inputs)
#define Bq   8
#define Cc   3
#define Hh   128     // h = H/8
#define Ww   256     // w = W/8
#define Mm   32
#define HW   (Hh*Ww) // 32768
#define HIMG 1024
#define WIMG 2048

typedef float f32x4 __attribute__((ext_vector_type(4)));

// ---------------------------------------------------------------------------
// Kernel 1: depth + channel-major normals from disp. Tiny (~2-3 us): reads
// disp (1 MB), writes depth+normal (4.2 MB, stays L3-hot for k_pool_planes).
// ---------------------------------------------------------------------------
__global__ void k_dn(const float* __restrict__ disp,
                     const float* __restrict__ intrs,
                     const float* __restrict__ baseline,
                     float* __restrict__ depth,
                     float* __restrict__ normal) {
    int idx = blockIdx.x * 256 + threadIdx.x;   // B*HW threads
    int b = idx >> 15;
    int p = idx & (HW - 1);
    int y = p >> 8;
    int x = p & (Ww - 1);
    float focal = 0.5f * (intrs[b * 9 + 0] + intrs[b * 9 + 4]);
    float k = baseline[b] * focal * (1.0f / 2048.0f);
    const float* db = disp + (size_t)b * HW;
    float Dc  = k / db[p];
    float Dxm = (x > 0)      ? k / db[p - 1]  : 0.0f;
    float Dxp = (x < Ww - 1) ? k / db[p + 1]  : 0.0f;
    float Dym = (y > 0)      ? k / db[p - Ww] : 0.0f;
    float Dyp = (y < Hh - 1) ? k / db[p + Ww] : 0.0f;
    float gx = 0.5f * (Dxp - Dxm);
    float gy = 0.5f * (Dyp - Dym);
    float invn = 1.0f / sqrtf(gx * gx + gy * gy + 1.0f);
    depth[idx] = Dc;
    // channel-major (3,h,w) per b — k_planes' torch-view channel-mixing
    // quirk depends on this exact flatten.
    float* nb = normal + (size_t)b * 3 * HW;
    nb[p]          = -gx * invn;
    nb[HW + p]     = -gy * invn;
    nb[2 * HW + p] =  invn;
}

// ---------------------------------------------------------------------------
// Kernel 2 (merged): blocks [0, Bq*Mm) do the per-(b,m) softmax-weighted
// depth/normal sums + homography (masks stream overlaps the img stream);
// blocks [Bq*Mm, ...) do the 8x8 average pool (dominant 201 MB HBM stream,
// non-temporal loads: img has zero reuse, keep L2/L3 for masks + img_p).
// Block-level role split = no wave divergence.
// ---------------------------------------------------------------------------
__global__ __launch_bounds__(512) void k_pool_planes(
        const float* __restrict__ img, float4* __restrict__ img_p,
        const float* __restrict__ masks,
        const float* __restrict__ depth, const float* __restrict__ normal,
        const float* __restrict__ intrs, const float* __restrict__ baseline,
        float* __restrict__ hm) {
    int blk = blockIdx.x;
    int tid = threadIdx.x;
    __shared__ float lds[5][8];
    if (blk < Bq * Mm) {
        // ---- planes role: one block per (b,m). Single pass (softmax
        // shift-invariance; masks~N(0,1), exp safe in fp32). Channel-mixed
        // normal reads n[3p..3p+2] for p=4i..4i+3 are exactly float4s
        // np[3i], np[3i+1], np[3i+2]. ----
        int bm = blk;
        int b = bm >> 5;
        const float4* mp = (const float4*)(masks + (size_t)bm * HW);
        const float4* dp = (const float4*)(depth + (size_t)b * HW);
        const float4* np = (const float4*)(normal + (size_t)b * 3 * HW);
        int lane = tid & 63, wid = tid >> 6;

        float se = 0.f, sd = 0.f, s0 = 0.f, s1 = 0.f, s2 = 0.f;
        #pragma unroll 4
        for (int kk = 0; kk < HW / 4 / 512; kk++) {   // exactly 16 iterations
            int i = tid + kk * 512;
            float4 mk  = mp[i];
            float4 d4  = dp[i];
            float4 n0v = np[3 * i], n1v = np[3 * i + 1], n2v = np[3 * i + 2];
            float e0 = __expf(mk.x), e1 = __expf(mk.y);
            float e2 = __expf(mk.z), e3 = __expf(mk.w);
            se += (e0 + e1) + (e2 + e3);
            sd = fmaf(e0, d4.x, fmaf(e1, d4.y, fmaf(e2, d4.z, fmaf(e3, d4.w, sd))));
            // p=4i+j reads normal linear idx 12i+3j .. 12i+3j+2:
            s0 = fmaf(e0, n0v.x, fmaf(e1, n0v.w, fmaf(e2, n1v.z, fmaf(e3, n2v.y, s0))));
            s1 = fmaf(e0, n0v.y, fmaf(e1, n1v.x, fmaf(e2, n1v.w, fmaf(e3, n2v.z, s1))));
            s2 = fmaf(e0, n0v.z, fmaf(e1, n1v.y, fmaf(e2, n2v.x, fmaf(e3, n2v.w, s2))));
        }
        float vals[5] = {se, sd, s0, s1, s2};
        #pragma unroll
        for (int j = 0; j < 5; j++) {
            float v = vals[j];
            #pragma unroll
            for (int off = 32; off; off >>= 1) v += __shfl_down(v, off, 64);
            if (lane == 0) lds[j][wid] = v;
        }
        __syncthreads();

        if (tid == 0) {
            float t[5];
            #pragma unroll
            for (int j = 0; j < 5; j++) {
                float r = 0.f;
                #pragma unroll
                for (int i = 0; i < 8; i++) r += lds[j][i];
                t[j] = r;
            }
            float inv_se = 1.0f / t[0];
            float pd = t[1] * inv_se;
            float n0 = t[2] * inv_se, n1 = t[3] * inv_se, n2 = t[4] * inv_se;
            const float* Km = intrs + b * 9;
            float a = Km[0], bb = Km[1], c = Km[2];
            float d = Km[3], e  = Km[4], f = Km[5];
            float g = Km[6], h2 = Km[7], i = Km[8];
            float det = a * (e * i - f * h2) - bb * (d * i - f * g) + c * (d * h2 - e * g);
            float invd = 1.0f / det;
            float ki[9] = {(e * i - f * h2) * invd, (c * h2 - bb * i) * invd, (bb * f - c * e) * invd,
                           (f * g - d * i) * invd, (a * i - c * g) * invd,  (c * d - a * f) * invd,
                           (d * h2 - e * g) * invd, (bb * g - a * h2) * invd, (a * e - bb * d) * invd};
            float s = baseline[b] / pd;
            // H_cal = I + s*e2*n^T (rows 0,1 identity; row 2 = (s n0, s n1, 1+s n2))
            float A[9] = {1.f, 0.f, 0.f, 0.f, 1.f, 0.f, s * n0, s * n1, 1.0f + s * n2};
            float T[9];
            #pragma unroll
            for (int r = 0; r < 3; r++)
                #pragma unroll
                for (int cc = 0; cc < 3; cc++)
                    T[r * 3 + cc] = Km[r * 3 + 0] * A[cc] + Km[r * 3 + 1] * A[3 + cc] + Km[r * 3 + 2] * A[6 + cc];
            #pragma unroll
            for (int r = 0; r < 2; r++)
                #pragma unroll
                for (int cc = 0; cc < 3; cc++)
                    hm[bm * 6 + r * 3 + cc] = T[r * 3 + 0] * ki[cc] + T[r * 3 + 1] * ki[3 + cc] + T[r * 3 + 2] * ki[6 + cc];
        }
    } else {
        // ---- pool role: one block per (b, 2-row group); thread = (row, x) ----
        int pb = blk - Bq * Mm;        // 0..511
        int b = pb >> 6;
        int y = ((pb & 63) << 1) | (tid >> 8);
        int x = tid & 255;
        float s[3];
        #pragma unroll
        for (int c = 0; c < 3; c++) {
            const float* base = img + ((size_t)(b * 3 + c) * HIMG + (size_t)y * 8) * WIMG + x * 8;
            float acc = 0.f;
            #pragma unroll
            for (int r = 0; r < 8; r++) {
                f32x4 u = __builtin_nontemporal_load((const f32x4*)(base + (size_t)r * WIMG));
                f32x4 v = __builtin_nontemporal_load((const f32x4*)(base + (size_t)r * WIMG + 4));
                acc += u.x + u.y + u.z + u.w + v.x + v.y + v.z + v.w;
            }
            s[c] = acc * (1.0f / 64.0f);
        }
        img_p[((size_t)(b * Hh + y)) * Ww + x] = make_float4(s[0], s[1], s[2], 0.f);
    }
}

// ---------------------------------------------------------------------------
// Kernel 3: per-pixel M-softmax blend with homography warp + bilinear sample
// (zeros padding, align_corners=True). 256-thread blocks, each thread owns
// TWO vertically-adjacent pixels: adjacent rows of the same plane sample
// overlapping source rows (d(iy)/dy ~= 1), so the second row's gathers hit
// L1 — cuts the ~537 MB L2 gather stream by ~25%. Round-1 showed blend is
// throughput- not latency-bound, so 8 waves/CU suffices; unroll-4 over
// planes keeps ~32 independent gathers in flight. Grid/sample math is
// bit-identical to the passing version (full fma per row, no increments).
// Validity folded into the bilinear weights (int clamps, one cmp per edge).
// ---------------------------------------------------------------------------
__global__ __launch_bounds__(256) void k_blend(const float* __restrict__ masks,
                        const float* __restrict__ hm,
                        const float4* __restrict__ img_p,
                        float* __restrict__ out) {
    int blk = blockIdx.x;          // b*64 + ytile
    int b = blk >> 6;
    int y0 = (blk & 63) << 1;      // rows y0, y0+1
    int x = threadIdx.x;
    __shared__ float hs[Mm * 6];
    if (x < Mm * 6) hs[x] = hm[b * Mm * 6 + x];
    __syncthreads();

    const float* mp = masks + (size_t)b * Mm * HW + (size_t)y0 * Ww + x;
    float xn  = (2.0f * x - (float)(Ww - 1)) * (1.0f / (float)(Ww - 1));
    float yn0 = (2.0f * y0 - (float)(Hh - 1)) * (1.0f / (float)(Hh - 1));
    float yn1 = (2.0f * (y0 + 1) - (float)(Hh - 1)) * (1.0f / (float)(Hh - 1));
    const float4* ip = img_p + (size_t)b * HW;

    float se0 = 0.f, a00 = 0.f, a01 = 0.f, a02 = 0.f;
    float se1 = 0.f, a10 = 0.f, a11 = 0.f, a12 = 0.f;
    #pragma unroll 4
    for (int m = 0; m < Mm; m++) {
        float mv0 = mp[(size_t)m * HW];
        float mv1 = mp[(size_t)m * HW + Ww];
        float e0 = __expf(mv0);
        float e1 = __expf(mv1);
        se0 += e0;
        se1 += e1;
        float h0 = hs[m * 6 + 0], h1 = hs[m * 6 + 1], h2 = hs[m * 6 + 2];
        float h3 = hs[m * 6 + 3], h4 = hs[m * 6 + 4], h5 = hs[m * 6 + 5];
        #define ROWSAMPLE(YN, E, SA0, SA1, SA2) do {                                \
            float gx = fmaf(h0, xn, fmaf(h1, (YN), h2));                            \
            float gy = fmaf(h3, xn, fmaf(h4, (YN), h5));                            \
            float ix = (gx + 1.0f) * ((float)(Ww - 1) * 0.5f);                      \
            float iy = (gy + 1.0f) * ((float)(Hh - 1) * 0.5f);                      \
            float x0f = floorf(ix), y0f = floorf(iy);                               \
            float wx1 = ix - x0f, wy1 = iy - y0f;                                   \
            float wx0 = 1.0f - wx1, wy0 = 1.0f - wy1;                               \
            int x0i = (int)x0f, y0i = (int)y0f;                                     \
            float vx0 = ((unsigned)x0i       < (unsigned)Ww) ? wx0 : 0.0f;          \
            float vx1 = ((unsigned)(x0i + 1) < (unsigned)Ww) ? wx1 : 0.0f;          \
            float vy0 = ((unsigned)y0i       < (unsigned)Hh) ? wy0 * (E) : 0.0f;    \
            float vy1 = ((unsigned)(y0i + 1) < (unsigned)Hh) ? wy1 * (E) : 0.0f;    \
            int xc0 = min(max(x0i, 0), Ww - 1);                                     \
            int xc1 = min(max(x0i + 1, 0), Ww - 1);                                 \
            int r0 = min(max(y0i, 0), Hh - 1) * Ww;                                 \
            int r1 = min(max(y0i + 1, 0), Hh - 1) * Ww;                             \
            float4 t00 = ip[r0 + xc0];                                              \
            float4 t10 = ip[r0 + xc1];                                              \
            float4 t01 = ip[r1 + xc0];                                              \
            float4 t11 = ip[r1 + xc1];                                              \
            float w00 = vx0 * vy0, w10 = vx1 * vy0;                                 \
            float w01 = vx0 * vy1, w11 = vx1 * vy1;                                 \
            SA0 = fmaf(w00, t00.x, fmaf(w10, t10.x, fmaf(w01, t01.x, fmaf(w11, t11.x, SA0)))); \
            SA1 = fmaf(w00, t00.y, fmaf(w10, t10.y, fmaf(w01, t01.y, fmaf(w11, t11.y, SA1)))); \
            SA2 = fmaf(w00, t00.z, fmaf(w10, t10.z, fmaf(w01, t01.z, fmaf(w11, t11.z, SA2)))); \
        } while (0)
        ROWSAMPLE(yn0, e0, a00, a01, a02);
        ROWSAMPLE(yn1, e1, a10, a11, a12);
        #undef ROWSAMPLE
    }
    int o = y0 * Ww + x;
    float* ob = out + (size_t)b * 3 * HW;
    float inv0 = 1.0f / se0;
    ob[o]          = a00 * inv0;
    ob[HW + o]     = a01 * inv0;
    ob[2 * HW + o] = a02 * inv0;
    float inv1 = 1.0f / se1;
    ob[o + Ww]          = a10 * inv1;
    ob[HW + o + Ww]     = a11 * inv1;
    ob[2 * HW + o + Ww] = a12 * inv1;
}

extern "C" void kernel_launch(void* const* d_in, const int* in_sizes, int n_in,
                              void* d_out, int out_size, void* d_ws, size_t ws_size,
                              hipStream_t stream) {
    const float* img      = (const float*)d_in[0];
    const float* masks    = (const float*)d_in[1];
    const float* disp     = (const float*)d_in[2];
    const float* intrs    = (const float*)d_in[3];
    const float* baseline = (const float*)d_in[4];
    float* out = (float*)d_out;

    // Workspace (floats): depth | normal | hm | img_p(float4) — offsets all
    // multiples of 4 floats so everything stays 16B-aligned. ~9.5 MB total.
    float* depth  = (float*)d_ws;                        // B*HW
    float* normal = depth + (size_t)Bq * HW;             // B*3*HW
    float* hm     = normal + (size_t)Bq * 3 * HW;        // B*M*6 = 1536
    float4* img_p = (float4*)(hm + (size_t)Bq * Mm * 6); // B*HW float4s

    // 3 dispatches: dn (tiny), then pool+planes merged (planes' mask stream
    // overlaps the 201 MB img stream; planes blocks dispatched first), then
    // blend (masks re-read is L3-resident).
    hipLaunchKernelGGL(k_dn, dim3(Bq * Hh), dim3(256), 0, stream,
                       disp, intrs, baseline, depth, normal);
    hipLaunchKernelGGL(k_pool_planes, dim3(Bq * Mm + Bq * Hh / 2), dim3(512), 0, stream,
                       img, img_p, masks, depth, normal, intrs, baseline, hm);
    hipLaunchKernelGGL(k_blend, dim3(Bq * Hh / 2), dim3(256), 0, stream,
                       masks, hm, img_p, out);
}

// Round 3
// 329.519 us; speedup vs baseline: 1.0287x; 1.0040x over previous
//
#include <hip/hip_runtime.h>
#include <math.h>

// Problem constants (fixed by setup_inputs)
#define Bq   8
#define Cc   3
#define Hh   128     // h = H/8
#define Ww   256     // w = W/8
#define Mm   32
#define HW   (Hh*Ww) // 32768
#define HIMG 1024
#define WIMG 2048

typedef float f32x4 __attribute__((ext_vector_type(4)));

// ---------------------------------------------------------------------------
// Pool role (shared by kernels 1 and 2): one block handles one (b, row-pair),
// thread = (row, x). 201 MB img stream with non-temporal loads (zero reuse;
// keep L2/L3 for masks + img_p). Packed float4 output for k_blend's gathers.
// ---------------------------------------------------------------------------
__device__ __forceinline__ void pool_pair(const float* __restrict__ img,
                                          float4* __restrict__ img_p,
                                          int pair, int tid) {
    int b = pair >> 6;
    int y = ((pair & 63) << 1) | (tid >> 8);
    int x = tid & 255;
    float s[3];
    #pragma unroll
    for (int c = 0; c < 3; c++) {
        const float* base = img + ((size_t)(b * 3 + c) * HIMG + (size_t)y * 8) * WIMG + x * 8;
        float acc = 0.f;
        #pragma unroll
        for (int r = 0; r < 8; r++) {
            f32x4 u = __builtin_nontemporal_load((const f32x4*)(base + (size_t)r * WIMG));
            f32x4 v = __builtin_nontemporal_load((const f32x4*)(base + (size_t)r * WIMG + 4));
            acc += u.x + u.y + u.z + u.w + v.x + v.y + v.z + v.w;
        }
        s[c] = acc * (1.0f / 64.0f);
    }
    img_p[((size_t)(b * Hh + y)) * Ww + x] = make_float4(s[0], s[1], s[2], 0.f);
}

// ---------------------------------------------------------------------------
// Kernel 1: blocks [0,256) = depth+normal from disp (tiny, memory-light —
// overlaps the img stream instead of running alone); blocks [256,512) =
// pool for the EVEN row-pairs (half the 201 MB stream). Block-level role
// split = no wave divergence.
// ---------------------------------------------------------------------------
__global__ __launch_bounds__(512) void k_dn_pool(
        const float* __restrict__ img, float4* __restrict__ img_p,
        const float* __restrict__ disp,
        const float* __restrict__ intrs, const float* __restrict__ baseline,
        float* __restrict__ depth, float* __restrict__ normal) {
    int blk = blockIdx.x;
    int tid = threadIdx.x;
    if (blk < 256) {
        // ---- dn role: 2 pixels per thread, coalesced (j-stride = 128K) ----
        int t = blk * 512 + tid;           // 0..131071
        #pragma unroll
        for (int j = 0; j < 2; j++) {
            int idx = t + j * 131072;      // B*HW = 262144 total
            int b = idx >> 15;
            int p = idx & (HW - 1);
            int y = p >> 8;
            int x = p & (Ww - 1);
            float focal = 0.5f * (intrs[b * 9 + 0] + intrs[b * 9 + 4]);
            float k = baseline[b] * focal * (1.0f / 2048.0f);
            const float* db = disp + (size_t)b * HW;
            float Dc  = k / db[p];
            float Dxm = (x > 0)      ? k / db[p - 1]  : 0.0f;
            float Dxp = (x < Ww - 1) ? k / db[p + 1]  : 0.0f;
            float Dym = (y > 0)      ? k / db[p - Ww] : 0.0f;
            float Dyp = (y < Hh - 1) ? k / db[p + Ww] : 0.0f;
            float gx = 0.5f * (Dxp - Dxm);
            float gy = 0.5f * (Dyp - Dym);
            float invn = 1.0f / sqrtf(gx * gx + gy * gy + 1.0f);
            depth[idx] = Dc;
            // channel-major (3,h,w) per b — k_planes' torch-view
            // channel-mixing quirk depends on this exact flatten.
            float* nb = normal + (size_t)b * 3 * HW;
            nb[p]          = -gx * invn;
            nb[HW + p]     = -gy * invn;
            nb[2 * HW + p] =  invn;
        }
    } else {
        pool_pair(img, img_p, (blk - 256) * 2, tid);      // even pairs
    }
}

// ---------------------------------------------------------------------------
// Kernel 2: blocks [0, Bq*Mm) = per-(b,m) softmax-weighted depth/normal sums
// + homography (masks stream overlaps the img stream); blocks [256,512) =
// pool for the ODD row-pairs (other half of the img stream).
// ---------------------------------------------------------------------------
__global__ __launch_bounds__(512) void k_pool_planes(
        const float* __restrict__ img, float4* __restrict__ img_p,
        const float* __restrict__ masks,
        const float* __restrict__ depth, const float* __restrict__ normal,
        const float* __restrict__ intrs, const float* __restrict__ baseline,
        float* __restrict__ hm) {
    int blk = blockIdx.x;
    int tid = threadIdx.x;
    __shared__ float lds[5][8];
    if (blk < Bq * Mm) {
        // ---- planes role: one block per (b,m). Single pass (softmax
        // shift-invariance; masks~N(0,1), exp safe in fp32). Channel-mixed
        // normal reads n[3p..3p+2] for p=4i..4i+3 are exactly float4s
        // np[3i], np[3i+1], np[3i+2]. ----
        int bm = blk;
        int b = bm >> 5;
        const float4* mp = (const float4*)(masks + (size_t)bm * HW);
        const float4* dp = (const float4*)(depth + (size_t)b * HW);
        const float4* np = (const float4*)(normal + (size_t)b * 3 * HW);
        int lane = tid & 63, wid = tid >> 6;

        float se = 0.f, sd = 0.f, s0 = 0.f, s1 = 0.f, s2 = 0.f;
        #pragma unroll 4
        for (int kk = 0; kk < HW / 4 / 512; kk++) {   // exactly 16 iterations
            int i = tid + kk * 512;
            float4 mk  = mp[i];
            float4 d4  = dp[i];
            float4 n0v = np[3 * i], n1v = np[3 * i + 1], n2v = np[3 * i + 2];
            float e0 = __expf(mk.x), e1 = __expf(mk.y);
            float e2 = __expf(mk.z), e3 = __expf(mk.w);
            se += (e0 + e1) + (e2 + e3);
            sd = fmaf(e0, d4.x, fmaf(e1, d4.y, fmaf(e2, d4.z, fmaf(e3, d4.w, sd))));
            // p=4i+j reads normal linear idx 12i+3j .. 12i+3j+2:
            s0 = fmaf(e0, n0v.x, fmaf(e1, n0v.w, fmaf(e2, n1v.z, fmaf(e3, n2v.y, s0))));
            s1 = fmaf(e0, n0v.y, fmaf(e1, n1v.x, fmaf(e2, n1v.w, fmaf(e3, n2v.z, s1))));
            s2 = fmaf(e0, n0v.z, fmaf(e1, n1v.y, fmaf(e2, n2v.x, fmaf(e3, n2v.w, s2))));
        }
        float vals[5] = {se, sd, s0, s1, s2};
        #pragma unroll
        for (int j = 0; j < 5; j++) {
            float v = vals[j];
            #pragma unroll
            for (int off = 32; off; off >>= 1) v += __shfl_down(v, off, 64);
            if (lane == 0) lds[j][wid] = v;
        }
        __syncthreads();

        if (tid == 0) {
            float t[5];
            #pragma unroll
            for (int j = 0; j < 5; j++) {
                float r = 0.f;
                #pragma unroll
                for (int i = 0; i < 8; i++) r += lds[j][i];
                t[j] = r;
            }
            float inv_se = 1.0f / t[0];
            float pd = t[1] * inv_se;
            float n0 = t[2] * inv_se, n1 = t[3] * inv_se, n2 = t[4] * inv_se;
            const float* Km = intrs + b * 9;
            float a = Km[0], bb = Km[1], c = Km[2];
            float d = Km[3], e  = Km[4], f = Km[5];
            float g = Km[6], h2 = Km[7], i = Km[8];
            float det = a * (e * i - f * h2) - bb * (d * i - f * g) + c * (d * h2 - e * g);
            float invd = 1.0f / det;
            float ki[9] = {(e * i - f * h2) * invd, (c * h2 - bb * i) * invd, (bb * f - c * e) * invd,
                           (f * g - d * i) * invd, (a * i - c * g) * invd,  (c * d - a * f) * invd,
                           (d * h2 - e * g) * invd, (bb * g - a * h2) * invd, (a * e - bb * d) * invd};
            float s = baseline[b] / pd;
            // H_cal = I + s*e2*n^T (rows 0,1 identity; row 2 = (s n0, s n1, 1+s n2))
            float A[9] = {1.f, 0.f, 0.f, 0.f, 1.f, 0.f, s * n0, s * n1, 1.0f + s * n2};
            float T[9];
            #pragma unroll
            for (int r = 0; r < 3; r++)
                #pragma unroll
                for (int cc = 0; cc < 3; cc++)
                    T[r * 3 + cc] = Km[r * 3 + 0] * A[cc] + Km[r * 3 + 1] * A[3 + cc] + Km[r * 3 + 2] * A[6 + cc];
            #pragma unroll
            for (int r = 0; r < 2; r++)
                #pragma unroll
                for (int cc = 0; cc < 3; cc++)
                    hm[bm * 6 + r * 3 + cc] = T[r * 3 + 0] * ki[cc] + T[r * 3 + 1] * ki[3 + cc] + T[r * 3 + 2] * ki[6 + cc];
        }
    } else {
        pool_pair(img, img_p, (blk - 256) * 2 + 1, tid);  // odd pairs
    }
}

// ---------------------------------------------------------------------------
// Kernel 3: per-pixel M-softmax blend with homography warp + bilinear sample
// (zeros padding, align_corners=True). 256-thread blocks, each thread owns
// TWO vertically-adjacent pixels: adjacent rows of the same plane sample
// overlapping source rows (d(iy)/dy ~= 1), so the second row's gathers hit
// L1 — cuts the ~537 MB L2 gather stream by ~25%. Blend is throughput- not
// latency-bound (round-1 A/B), so 8 waves/CU suffices; unroll-4 over planes
// keeps ~32 independent gathers in flight. Validity folded into the
// bilinear weights (int clamps, one cmp per edge). out stored non-temporal
// (never re-read).
// ---------------------------------------------------------------------------
__global__ __launch_bounds__(256) void k_blend(const float* __restrict__ masks,
                        const float* __restrict__ hm,
                        const float4* __restrict__ img_p,
                        float* __restrict__ out) {
    int blk = blockIdx.x;          // b*64 + ytile
    int b = blk >> 6;
    int y0 = (blk & 63) << 1;      // rows y0, y0+1
    int x = threadIdx.x;
    __shared__ float hs[Mm * 6];
    if (x < Mm * 6) hs[x] = hm[b * Mm * 6 + x];
    __syncthreads();

    const float* mp = masks + (size_t)b * Mm * HW + (size_t)y0 * Ww + x;
    float xn  = (2.0f * x - (float)(Ww - 1)) * (1.0f / (float)(Ww - 1));
    float yn0 = (2.0f * y0 - (float)(Hh - 1)) * (1.0f / (float)(Hh - 1));
    float yn1 = (2.0f * (y0 + 1) - (float)(Hh - 1)) * (1.0f / (float)(Hh - 1));
    const float4* ip = img_p + (size_t)b * HW;

    float se0 = 0.f, a00 = 0.f, a01 = 0.f, a02 = 0.f;
    float se1 = 0.f, a10 = 0.f, a11 = 0.f, a12 = 0.f;
    #pragma unroll 4
    for (int m = 0; m < Mm; m++) {
        float mv0 = mp[(size_t)m * HW];
        float mv1 = mp[(size_t)m * HW + Ww];
        float e0 = __expf(mv0);
        float e1 = __expf(mv1);
        se0 += e0;
        se1 += e1;
        float h0 = hs[m * 6 + 0], h1 = hs[m * 6 + 1], h2 = hs[m * 6 + 2];
        float h3 = hs[m * 6 + 3], h4 = hs[m * 6 + 4], h5 = hs[m * 6 + 5];
        #define ROWSAMPLE(YN, E, SA0, SA1, SA2) do {                                \
            float gx = fmaf(h0, xn, fmaf(h1, (YN), h2));                            \
            float gy = fmaf(h3, xn, fmaf(h4, (YN), h5));                            \
            float ix = (gx + 1.0f) * ((float)(Ww - 1) * 0.5f);                      \
            float iy = (gy + 1.0f) * ((float)(Hh - 1) * 0.5f);                      \
            float x0f = floorf(ix), y0f = floorf(iy);                               \
            float wx1 = ix - x0f, wy1 = iy - y0f;                                   \
            float wx0 = 1.0f - wx1, wy0 = 1.0f - wy1;                               \
            int x0i = (int)x0f, y0i = (int)y0f;                                     \
            float vx0 = ((unsigned)x0i       < (unsigned)Ww) ? wx0 : 0.0f;          \
            float vx1 = ((unsigned)(x0i + 1) < (unsigned)Ww) ? wx1 : 0.0f;          \
            float vy0 = ((unsigned)y0i       < (unsigned)Hh) ? wy0 * (E) : 0.0f;    \
            float vy1 = ((unsigned)(y0i + 1) < (unsigned)Hh) ? wy1 * (E) : 0.0f;    \
            int xc0 = min(max(x0i, 0), Ww - 1);                                     \
            int xc1 = min(max(x0i + 1, 0), Ww - 1);                                 \
            int r0 = min(max(y0i, 0), Hh - 1) * Ww;                                 \
            int r1 = min(max(y0i + 1, 0), Hh - 1) * Ww;                             \
            float4 t00 = ip[r0 + xc0];                                              \
            float4 t10 = ip[r0 + xc1];                                              \
            float4 t01 = ip[r1 + xc0];                                              \
            float4 t11 = ip[r1 + xc1];                                              \
            float w00 = vx0 * vy0, w10 = vx1 * vy0;                                 \
            float w01 = vx0 * vy1, w11 = vx1 * vy1;                                 \
            SA0 = fmaf(w00, t00.x, fmaf(w10, t10.x, fmaf(w01, t01.x, fmaf(w11, t11.x, SA0)))); \
            SA1 = fmaf(w00, t00.y, fmaf(w10, t10.y, fmaf(w01, t01.y, fmaf(w11, t11.y, SA1)))); \
            SA2 = fmaf(w00, t00.z, fmaf(w10, t10.z, fmaf(w01, t01.z, fmaf(w11, t11.z, SA2)))); \
        } while (0)
        ROWSAMPLE(yn0, e0, a00, a01, a02);
        ROWSAMPLE(yn1, e1, a10, a11, a12);
        #undef ROWSAMPLE
    }
    int o = y0 * Ww + x;
    float* ob = out + (size_t)b * 3 * HW;
    float inv0 = 1.0f / se0;
    float inv1 = 1.0f / se1;
    __builtin_nontemporal_store(a00 * inv0, ob + o);
    __builtin_nontemporal_store(a01 * inv0, ob + HW + o);
    __builtin_nontemporal_store(a02 * inv0, ob + 2 * HW + o);
    __builtin_nontemporal_store(a10 * inv1, ob + o + Ww);
    __builtin_nontemporal_store(a11 * inv1, ob + HW + o + Ww);
    __builtin_nontemporal_store(a12 * inv1, ob + 2 * HW + o + Ww);
}

extern "C" void kernel_launch(void* const* d_in, const int* in_sizes, int n_in,
                              void* d_out, int out_size, void* d_ws, size_t ws_size,
                              hipStream_t stream) {
    const float* img      = (const float*)d_in[0];
    const float* masks    = (const float*)d_in[1];
    const float* disp     = (const float*)d_in[2];
    const float* intrs    = (const float*)d_in[3];
    const float* baseline = (const float*)d_in[4];
    float* out = (float*)d_out;

    // Workspace (floats): depth | normal | hm | img_p(float4) — offsets all
    // multiples of 4 floats so everything stays 16B-aligned. ~9.5 MB total.
    float* depth  = (float*)d_ws;                        // B*HW
    float* normal = depth + (size_t)Bq * HW;             // B*3*HW
    float* hm     = normal + (size_t)Bq * 3 * HW;        // B*M*6 = 1536
    float4* img_p = (float4*)(hm + (size_t)Bq * Mm * 6); // B*HW float4s

    // 3 dispatches, every one with a pool co-tenant so the 201 MB img stream
    // is never idle: {dn + pool evens}, {planes + pool odds}, {blend}.
    hipLaunchKernelGGL(k_dn_pool, dim3(512), dim3(512), 0, stream,
                       img, img_p, disp, intrs, baseline, depth, normal);
    hipLaunchKernelGGL(k_pool_planes, dim3(512), dim3(512), 0, stream,
                       img, img_p, masks, depth, normal, intrs, baseline, hm);
    hipLaunchKernelGGL(k_blend, dim3(Bq * Hh / 2), dim3(256), 0, stream,
                       masks, hm, img_p, out);
}